// Round 5
// baseline (193.149 us; speedup 1.0000x reference)
//
#include <hip/hip_runtime.h>
#include <math.h>

// EdgeConv, factorized:
//   A[i] = x[i] @ (W1_top - W1_bot) + b1        (64-dim f16, per node)
//   B[j] = x[j] @ W1_bot                        (64-dim bf16, per node)
//   agg1[i] = sum_{e: dst=i} relu(A[i] + B[src_e])
//   out[i]  = tanh(agg1[i] @ W2 + deg_i * b2)
//
// R14 resubmit (R15): container-level infra failure, no counters; source
// re-audited (bounds/sync/grid/LDS) -- unchanged experiment.
// R13 -> R14: prep was latency-bound (floor ~15 us vs 55 measured; FETCH
// only 19.6 MB -> reads L3-hot).  Node blocks now process 2 tiles (128
// nodes) with a software pipeline: tile1 x-loads issue before tile0
// compute, pack after -> stage latency hides under fdot2 work; per-block
// fixed cost halves.  wprep_k eliminated: each prep block converts W1
// into LDS itself (L3-hot), fused_agg converts W2 itself -- removes a
// serial 1-block kernel from the stream.  Bin branch unchanged (EPB 4096),
// interleave 3 node : 1 bin.

#define FDIM 64
#define BN 64             // nodes per bucket (bin/agg granularity)
#define BSH 6             // log2(BN)
#define CAPB 1024         // bucket capacity (mean 768, +9 sigma)
#define MAXB 2048         // LDS bucket-counter array bound in bin branch
#define EPB 4096          // edges per bin block
#define NT 64             // nodes per compute tile
#define TPB 2             // tiles per node block (pipelined)
#define PRE_SMEM 32768    // bytes: Wch 16384 + xs 2*8192 (> bin 16384)

typedef unsigned int u32;
typedef unsigned short u16;
typedef _Float16 hf;
typedef _Float16 h2 __attribute__((ext_vector_type(2)));

__device__ __forceinline__ float bf_lo(u32 u) {
    union { u32 i; float f; } c; c.i = u << 16; return c.f;
}
__device__ __forceinline__ float bf_hi(u32 u) {
    union { u32 i; float f; } c; c.i = u & 0xffff0000u; return c.f;
}
__device__ __forceinline__ u32 f2bf_rne(float f) {
    union { float f; u32 u; } c; c.f = f;
    u32 u = c.u;
    u += 0x7fffu + ((u >> 16) & 1u);   // round-to-nearest-even
    return u >> 16;
}
__device__ __forceinline__ u32 f2h(float f) {
    union { u16 s; hf h; } c; c.h = (hf)f; return (u32)c.s;
}
__device__ __forceinline__ float h_lo(u32 u) {
    union { u16 s; hf h; } c; c.s = (u16)(u & 0xffffu); return (float)c.h;
}
__device__ __forceinline__ float h_hi(u32 u) {
    union { u16 s; hf h; } c; c.s = (u16)(u >> 16); return (float)c.h;
}
__device__ __forceinline__ h2 u2h2(u32 u) {
    union { u32 u; h2 h; } c; c.u = u; return c.h;
}

// ---------------------------------------------------------------------------
// Kernel 1: merged prep.  blockIdx%4==3 -> bin branch, else node_pre
// (2 pipelined 64-node tiles per block).
// ---------------------------------------------------------------------------
__global__ __launch_bounds__(256) void prep_k(
    const float* __restrict__ x, const float* __restrict__ W1,
    const float* __restrict__ b1, u16* __restrict__ Ah,
    u16* __restrict__ Bmh, const int* __restrict__ ei,
    u32* __restrict__ slotB, int* __restrict__ gcnt,
    int N, int E, int NB, int nPre, int nBin)
{
    __shared__ __align__(16) char smem[PRE_SMEM];
    const int idx = blockIdx.x;
    const int tid = threadIdx.x;

    if ((idx & 3) == 3) {
        // ---------------- bin branch ----------------
        const int bb = idx >> 2;
        if (bb >= nBin) return;
        int* histL = (int*)smem;
        int* gbase = histL + MAXB;
        const int e0 = bb * EPB;

        for (int j = tid; j < NB; j += 256) histL[j] = 0;
        __syncthreads();

        #pragma unroll 8
        for (int i = 0; i < EPB / 256; ++i) {
            int e = e0 + i * 256 + tid;
            if (e < E) {
                int d = ei[E + e];
                atomicAdd(&histL[d >> BSH], 1);
            }
        }
        __syncthreads();

        for (int j = tid; j < NB; j += 256) {
            int h = histL[j];
            gbase[j] = (h > 0) ? atomicAdd(&gcnt[j], h) : 0;
            histL[j] = 0;                 // reuse as local append pos
        }
        __syncthreads();

        #pragma unroll 8
        for (int i = 0; i < EPB / 256; ++i) {
            int e = e0 + i * 256 + tid;
            if (e < E) {
                int s = ei[e];
                int d = ei[E + e];
                int b = d >> BSH;
                int pos = gbase[b] + atomicAdd(&histL[b], 1);
                if (pos < CAPB)
                    slotB[(size_t)b * CAPB + pos] =
                        ((u32)(d & (BN - 1)) << 20) | (u32)s;
            }
        }
        return;
    }

    // ---------------- node_pre branch ----------------
    const int pb = idx - (idx >> 2);
    if (pb >= nPre) return;
    u32 (*Wch)[128] = (u32(*)[128])smem;                 // 16384 B, k-pair rows
    u32* xs = (u32*)(smem + 16384);                      // [2][32][64] u32, XOR-swz

    const int node0 = pb * (NT * TPB);
    const float4* X4 = (const float4*)x;

    // Issue tile0 x loads (coalesced float4) -- latency hides under W convert.
    float4 xv[4];
    #pragma unroll
    for (int it = 0; it < 4; ++it) {
        int i = it * 256 + tid;            // 0..1023
        int n = i >> 4, k4 = i & 15;
        int gn = node0 + n;
        xv[it] = (gn < N) ? X4[(size_t)gn * 16 + k4]
                          : make_float4(0.f, 0.f, 0.f, 0.f);
    }

    // Convert W1 -> f16 k-pair layout in LDS (L2/L3-hot reads):
    // Wch[kk][c] = f16pair over k of: c<64 -> (W1t-W1b)[*][c]; c>=64 -> W1b.
    for (int i = tid; i < 4096; i += 256) {
        int kk = i >> 7, c = i & 127;
        int k0 = 2 * kk, k1 = k0 + 1;
        float a0, a1;
        if (c < 64) {
            a0 = W1[k0 * 64 + c] - W1[(64 + k0) * 64 + c];
            a1 = W1[k1 * 64 + c] - W1[(64 + k1) * 64 + c];
        } else {
            int cc = c - 64;
            a0 = W1[(64 + k0) * 64 + cc];
            a1 = W1[(64 + k1) * 64 + cc];
        }
        Wch[kk][c] = f2h(a0) | (f2h(a1) << 16);
    }

    // Pack tile0 into xs[0]: k-major, 16B-granule XOR swizzle (2-way = free).
    #pragma unroll
    for (int it = 0; it < 4; ++it) {
        int i = it * 256 + tid;
        int n = i >> 4, k4 = i & 15;
        int r0 = 2 * k4, r1 = r0 + 1;
        int g = n >> 2, lo = n & 3;
        xs[r0 * 64 + (((g ^ (r0 & 15)) << 2) | lo)] = f2h(xv[it].x) | (f2h(xv[it].y) << 16);
        xs[r1 * 64 + (((g ^ (r1 & 15)) << 2) | lo)] = f2h(xv[it].z) | (f2h(xv[it].w) << 16);
    }
    __syncthreads();

    // Issue tile1 x loads NOW; they land while tile0 computes.
    #pragma unroll
    for (int it = 0; it < 4; ++it) {
        int i = it * 256 + tid;
        int n = i >> 4, k4 = i & 15;
        int gn = node0 + NT + n;
        xv[it] = (gn < N) ? X4[(size_t)gn * 16 + k4]
                          : make_float4(0.f, 0.f, 0.f, 0.f);
    }

    const int ng = tid & 15, cg = tid >> 4;
    const int n0 = ng * 4, c0 = cg * 8;

    auto compute_store = [&](const u32* xst, int base) {
        float acc[4][8];
        #pragma unroll
        for (int ci = 0; ci < 8; ++ci) {
            float init = (c0 < 64) ? b1[c0 + ci] : 0.f;
            #pragma unroll
            for (int ni = 0; ni < 4; ++ni) acc[ni][ci] = init;
        }
        // per kk: one b128 x read (4 nodes' k-pairs) + 2 b128 W reads + 32 fdot2
        #pragma unroll 4
        for (int kk = 0; kk < 32; ++kk) {
            uint4 xq = *(const uint4*)&xst[kk * 64 + ((ng ^ (kk & 15)) << 2)];
            uint4 w0 = *(const uint4*)&Wch[kk][c0];
            uint4 w1 = *(const uint4*)&Wch[kk][c0 + 4];
            h2 wv[8] = {u2h2(w0.x), u2h2(w0.y), u2h2(w0.z), u2h2(w0.w),
                        u2h2(w1.x), u2h2(w1.y), u2h2(w1.z), u2h2(w1.w)};
            u32 xq4[4] = {xq.x, xq.y, xq.z, xq.w};
            #pragma unroll
            for (int ni = 0; ni < 4; ++ni) {
                h2 xh = u2h2(xq4[ni]);
                #pragma unroll
                for (int ci = 0; ci < 8; ++ci)
                    acc[ni][ci] = __builtin_amdgcn_fdot2(xh, wv[ci], acc[ni][ci], false);
            }
        }
        #pragma unroll
        for (int ni = 0; ni < 4; ++ni) {
            int n = base + n0 + ni;
            if (n >= N) break;
            if (c0 < 64) {
                uint4 pk;
                pk.x = f2h(acc[ni][0]) | (f2h(acc[ni][1]) << 16);
                pk.y = f2h(acc[ni][2]) | (f2h(acc[ni][3]) << 16);
                pk.z = f2h(acc[ni][4]) | (f2h(acc[ni][5]) << 16);
                pk.w = f2h(acc[ni][6]) | (f2h(acc[ni][7]) << 16);
                *(uint4*)&Ah[(size_t)n * 64 + c0] = pk;
            } else {
                uint4 pk;
                pk.x = f2bf_rne(acc[ni][0]) | (f2bf_rne(acc[ni][1]) << 16);
                pk.y = f2bf_rne(acc[ni][2]) | (f2bf_rne(acc[ni][3]) << 16);
                pk.z = f2bf_rne(acc[ni][4]) | (f2bf_rne(acc[ni][5]) << 16);
                pk.w = f2bf_rne(acc[ni][6]) | (f2bf_rne(acc[ni][7]) << 16);
                *(uint4*)&Bmh[(size_t)n * 64 + (c0 - 64)] = pk;
            }
        }
    };

    // ---- tile0 compute (tile1 loads in flight) ----
    compute_store(xs, node0);

    // Pack tile1 into xs[1] (no sync needed: disjoint buffer).
    u32* xs1 = xs + 2048;
    #pragma unroll
    for (int it = 0; it < 4; ++it) {
        int i = it * 256 + tid;
        int n = i >> 4, k4 = i & 15;
        int r0 = 2 * k4, r1 = r0 + 1;
        int g = n >> 2, lo = n & 3;
        xs1[r0 * 64 + (((g ^ (r0 & 15)) << 2) | lo)] = f2h(xv[it].x) | (f2h(xv[it].y) << 16);
        xs1[r1 * 64 + (((g ^ (r1 & 15)) << 2) | lo)] = f2h(xv[it].z) | (f2h(xv[it].w) << 16);
    }
    __syncthreads();

    // ---- tile1 compute ----
    compute_store(xs1, node0 + NT);
}

// ---------------------------------------------------------------------------
// Kernel 2: per-bucket CSR build + aggregate + W2 GEMM + tanh.
// BN=64: LDS ~22.6 KB -> 7 blocks/CU; grid 1563 blocks (~6.1/CU).
// W2 converted f32->f16 per block (L2/L3-hot; replaces W2hg).
// ---------------------------------------------------------------------------
__device__ __forceinline__ float4 relu4add(float4 acc, float4 a, float4 b) {
    acc.x += fmaxf(a.x + b.x, 0.f);
    acc.y += fmaxf(a.y + b.y, 0.f);
    acc.z += fmaxf(a.z + b.z, 0.f);
    acc.w += fmaxf(a.w + b.w, 0.f);
    return acc;
}
__device__ __forceinline__ float4 relu4add_m(float4 acc, float4 a, float4 b, bool m) {
    acc.x += m ? fmaxf(a.x + b.x, 0.f) : 0.f;
    acc.y += m ? fmaxf(a.y + b.y, 0.f) : 0.f;
    acc.z += m ? fmaxf(a.z + b.z, 0.f) : 0.f;
    acc.w += m ? fmaxf(a.w + b.w, 0.f) : 0.f;
    return acc;
}
__device__ __forceinline__ float4 bf4(uint2 u) {
    return make_float4(bf_lo(u.x), bf_hi(u.x), bf_lo(u.y), bf_hi(u.y));
}

__global__ __launch_bounds__(256) void fused_agg(
    const u16* __restrict__ Ah, const u16* __restrict__ Bmh,
    const u32* __restrict__ slotB, const int* __restrict__ gcnt,
    const float* __restrict__ W2, const float* __restrict__ b2,
    float* __restrict__ out, int N)
{
    __shared__ __align__(16) u32 W2h[64][34];        // f16-packed W2, 8.7 KB
    __shared__ __align__(16) u32 pool[BN * 17 * 2];  // 8.7 KB: eStage then aggTb
    __shared__ u32 csrS[CAPB];                       // 4 KB
    __shared__ int histL[BN];
    __shared__ int rowO[BN + 1];
    __shared__ int ofs[BN];
    __shared__ float b2s[64];

    u32* eStage = pool;                              // [CAPB] (phase: CSR build)
    uint2* aggTb = (uint2*)pool;                     // [BN][17] (phase: agg)

    const int tid = threadIdx.x;
    const int b = blockIdx.x;
    const int node0 = b * BN;
    const int cntB = min(gcnt[b], CAPB);

    // Convert W2 f32 -> f16 pairs in LDS (coalesced, L2/L3-hot).
    for (int i = tid; i < 2048; i += 256) {
        int k = i >> 5, c2 = i & 31;
        W2h[k][c2] = f2h(W2[k * 64 + 2 * c2]) | (f2h(W2[k * 64 + 2 * c2 + 1]) << 16);
    }
    if (tid < 64) b2s[tid] = b2[tid];
    if (tid < BN) histL[tid] = 0;
    __syncthreads();

    for (int i = tid; i < cntB; i += 256) {
        u32 e = slotB[(size_t)b * CAPB + i];
        eStage[i] = e;
        atomicAdd(&histL[e >> 20], 1);
    }
    __syncthreads();

    if (tid < 32) {                                  // exclusive scan of 64 bins
        int l = tid;
        int h0 = histL[2 * l], h1 = histL[2 * l + 1];
        int s = h0 + h1, inc = s;
        #pragma unroll
        for (int off = 1; off < 32; off <<= 1) {
            int t = __shfl_up(inc, off);
            if (l >= off) inc += t;
        }
        int base = inc - s;
        rowO[2 * l] = base; rowO[2 * l + 1] = base + h0;
        ofs[2 * l] = base;  ofs[2 * l + 1] = base + h0;
        if (l == 31) rowO[BN] = inc;
    }
    __syncthreads();

    for (int i = tid; i < cntB; i += 256) {
        u32 e = eStage[i];
        int pos = atomicAdd(&ofs[e >> 20], 1);
        csrS[pos] = e & 0xFFFFFu;
    }
    __syncthreads();                                 // eStage dead; aggTb live

    // ---- Phase 1: gather-aggregate, 8 independent gathers per round ----
    {
        const int q = tid & 15, ng = tid >> 4;
        const uint2* __restrict__ B2 = (const uint2*)Bmh;
        const uint2* __restrict__ A2 = (const uint2*)Ah;
        #pragma unroll
        for (int h = 0; h < 4; ++h) {
            int nl = ng + h * 16;
            int gn = node0 + nl;
            int start = rowO[nl];
            int d = (gn < N) ? (rowO[nl + 1] - start) : 0;
            float4 a = make_float4(0.f, 0.f, 0.f, 0.f);
            if (gn < N) {
                uint2 ua = A2[(size_t)gn * 16 + q];
                a = make_float4(h_lo(ua.x), h_hi(ua.x), h_lo(ua.y), h_hi(ua.y));
            }
            float4 acc = make_float4(0.f, 0.f, 0.f, 0.f);

            int j = 0;
            for (; j + 8 <= d; j += 8) {             // exact 8-batches
                int ss[8];
                uint2 bb[8];
                #pragma unroll
                for (int t = 0; t < 8; ++t) ss[t] = csrS[start + j + t];
                #pragma unroll
                for (int t = 0; t < 8; ++t) bb[t] = B2[(size_t)ss[t] * 16 + q];
                #pragma unroll
                for (int t = 0; t < 8; ++t) acc = relu4add(acc, a, bf4(bb[t]));
            }
            if (j < d) {                             // masked 8-tail (clamped idx)
                int ss[8];
                uint2 bb[8];
                #pragma unroll
                for (int t = 0; t < 8; ++t) ss[t] = csrS[start + min(j + t, d - 1)];
                #pragma unroll
                for (int t = 0; t < 8; ++t) bb[t] = B2[(size_t)ss[t] * 16 + q];
                acc = relu4add(acc, a, bf4(bb[0]));
                #pragma unroll
                for (int t = 1; t < 8; ++t)
                    acc = relu4add_m(acc, a, bf4(bb[t]), j + t < d);
            }
            uint2 pk;
            pk.x = f2h(acc.x) | (f2h(acc.y) << 16);
            pk.y = f2h(acc.z) | (f2h(acc.w) << 16);
            aggTb[nl * 17 + q] = pk;
        }
    }
    __syncthreads();

    // ---- Phase 2: [64x64] @ W2 + deg*b2, tanh; W2 f16 from LDS ----
    {
        const int cg = tid & 15, g = tid >> 4;       // g: 0..15 -> 64 nodes
        const int c0 = cg * 4;
        const int nb0 = g * 4;                       // nodes nb0..nb0+3
        float o[4][4];
        #pragma unroll
        for (int ni = 0; ni < 4; ++ni) {
            float dg = (float)(rowO[nb0 + ni + 1] - rowO[nb0 + ni]);
            #pragma unroll
            for (int ci = 0; ci < 4; ++ci) o[ni][ci] = dg * b2s[c0 + ci];
        }
        #pragma unroll 2
        for (int kc = 0; kc < 16; ++kc) {
            uint2 u0 = aggTb[(nb0 + 0) * 17 + kc];
            uint2 u1 = aggTb[(nb0 + 1) * 17 + kc];
            uint2 u2 = aggTb[(nb0 + 2) * 17 + kc];
            uint2 u3 = aggTb[(nb0 + 3) * 17 + kc];
            #pragma unroll
            for (int kk = 0; kk < 4; ++kk) {
                uint2 w2p = *(const uint2*)&W2h[kc * 4 + kk][cg * 2];
                float wv[4] = {h_lo(w2p.x), h_hi(w2p.x), h_lo(w2p.y), h_hi(w2p.y)};
                float a0 = (kk < 2) ? ((kk == 0) ? h_lo(u0.x) : h_hi(u0.x))
                                    : ((kk == 2) ? h_lo(u0.y) : h_hi(u0.y));
                float a1 = (kk < 2) ? ((kk == 0) ? h_lo(u1.x) : h_hi(u1.x))
                                    : ((kk == 2) ? h_lo(u1.y) : h_hi(u1.y));
                float a2 = (kk < 2) ? ((kk == 0) ? h_lo(u2.x) : h_hi(u2.x))
                                    : ((kk == 2) ? h_lo(u2.y) : h_hi(u2.y));
                float a3 = (kk < 2) ? ((kk == 0) ? h_lo(u3.x) : h_hi(u3.x))
                                    : ((kk == 2) ? h_lo(u3.y) : h_hi(u3.y));
                #pragma unroll
                for (int ci = 0; ci < 4; ++ci) {
                    o[0][ci] += a0 * wv[ci];
                    o[1][ci] += a1 * wv[ci];
                    o[2][ci] += a2 * wv[ci];
                    o[3][ci] += a3 * wv[ci];
                }
            }
        }
        #pragma unroll
        for (int ni = 0; ni < 4; ++ni) {
            int gn = node0 + nb0 + ni;
            if (gn < N) {
                float4 r = make_float4(tanhf(o[ni][0]), tanhf(o[ni][1]),
                                       tanhf(o[ni][2]), tanhf(o[ni][3]));
                ((float4*)out)[(size_t)gn * 16 + cg] = r;
            }
        }
    }
}

// ---------------------------------------------------------------------------
extern "C" void kernel_launch(void* const* d_in, const int* in_sizes, int n_in,
                              void* d_out, int out_size, void* d_ws, size_t ws_size,
                              hipStream_t stream)
{
    const float* x  = (const float*)d_in[0];
    const int*   ei = (const int*)d_in[1];     // [2,E]: row0=src, row1=dst
    const float* W1 = (const float*)d_in[2];   // [128,64]
    const float* b1 = (const float*)d_in[3];   // [64]
    const float* W2 = (const float*)d_in[4];   // [64,64]
    const float* b2 = (const float*)d_in[5];   // [64]
    float* out = (float*)d_out;

    const int N = in_sizes[0] / FDIM;          // 100000
    const int E = in_sizes[1] / 2;             // 1200000
    const int NB = (N + BN - 1) / BN;          // 1563 buckets

    // Workspace (re-poisoned 0xAA every call; gcnt zeroed below):
    u16*   Ah    = (u16*)d_ws;                          // N*64 f16  = 12.8 MB
    u16*   Bmh   = Ah + (size_t)N * FDIM;               // N*64 bf16 = 12.8 MB
    u32*   slotB = (u32*)(Bmh + (size_t)N * FDIM);      // NB*CAPB u32 = 6.4 MB
    int*   gcnt  = (int*)(slotB + (size_t)NB * CAPB);   // NB i32

    hipMemsetAsync(gcnt, 0, (size_t)NB * sizeof(int), stream);

    // Interleaved heterogeneous grid: 1 bin block per 4 (idx%4==3), rest pre.
    const int nPre = (N + NT * TPB - 1) / (NT * TPB);  // 782
    const int nBin = (E + EPB - 1) / EPB;              // 293
    int T = 4 * nBin;                                  // 1172
    while (T - T / 4 < nPre) ++T;

    prep_k<<<T, 256, 0, stream>>>(x, W1, b1, Ah, Bmh, ei, slotB, gcnt,
                                  N, E, NB, nPre, nBin);
    fused_agg<<<NB, 256, 0, stream>>>(Ah, Bmh, slotB, gcnt, W2, b2, out, N);
}

// Round 6
// 185.599 us; speedup vs baseline: 1.0407x; 1.0407x over previous
//
#include <hip/hip_runtime.h>
#include <math.h>

// EdgeConv, factorized:
//   A[i] = x[i] @ (W1_top - W1_bot) + b1        (computed in fused_agg, f32 regs)
//   B[j] = x[j] @ W1_bot                        (64-dim bf16, per node, prep_k)
//   agg1[i] = sum_{e: dst=i} relu(A[i] + B[src_e])
//   out[i]  = tanh(agg1[i] @ W2 + deg_i * b2)
//
// R15 -> R16: 2-tile pipeline regressed (LDS 32KB -> 4 blocks/CU, longer
// serial chain; Occ 24->18%, prep 55->80us).  Revert to R13 block structure
// and instead SHRINK prep: A-GEMM moved into fused_agg (computed per-tile
// into registers, hidden under gather latency; Ah 12.8MB write+read
// eliminated).  prep computes B only: fdot2/thread halves, PRE_SMEM 16KB
// -> 8-9 blocks/CU.  fused_agg stages x-tile+Wdiff in a 16KB LDS region
// reused as csrS/eStage/aggTb after A-compute (26.4KB total, 6 blocks/CU).

#define FDIM 64
#define BN 64             // nodes per bucket (bin/agg granularity)
#define BSH 6             // log2(BN)
#define CAPB 1024         // bucket capacity (mean 768, +9 sigma)
#define MAXB 2048         // LDS bucket-counter array bound in bin branch
#define EPB 4096          // edges per bin block
#define PRE_SMEM 16384    // bytes: Wch 8192 + xs 8192  (== bin 16384)

typedef unsigned int u32;
typedef unsigned short u16;
typedef _Float16 hf;
typedef _Float16 h2 __attribute__((ext_vector_type(2)));

__device__ __forceinline__ float bf_lo(u32 u) {
    union { u32 i; float f; } c; c.i = u << 16; return c.f;
}
__device__ __forceinline__ float bf_hi(u32 u) {
    union { u32 i; float f; } c; c.i = u & 0xffff0000u; return c.f;
}
__device__ __forceinline__ u32 f2bf_rne(float f) {
    union { float f; u32 u; } c; c.f = f;
    u32 u = c.u;
    u += 0x7fffu + ((u >> 16) & 1u);   // round-to-nearest-even
    return u >> 16;
}
__device__ __forceinline__ u32 f2h(float f) {
    union { u16 s; hf h; } c; c.h = (hf)f; return (u32)c.s;
}
__device__ __forceinline__ float h_lo(u32 u) {
    union { u16 s; hf h; } c; c.s = (u16)(u & 0xffffu); return (float)c.h;
}
__device__ __forceinline__ float h_hi(u32 u) {
    union { u16 s; hf h; } c; c.s = (u16)(u >> 16); return (float)c.h;
}
__device__ __forceinline__ h2 u2h2(u32 u) {
    union { u32 u; h2 h; } c; c.u = u; return c.h;
}

// ---------------------------------------------------------------------------
// Kernel 1: merged prep.  blockIdx%6==5 -> bin branch, else node_pre
// (B-GEMM only: 64 nodes x 64 cols).
// ---------------------------------------------------------------------------
__global__ __launch_bounds__(256) void prep_k(
    const float* __restrict__ x, const float* __restrict__ W1,
    u16* __restrict__ Bmh, const int* __restrict__ ei,
    u32* __restrict__ slotB, int* __restrict__ gcnt,
    int N, int E, int NB, int nPre, int nBin)
{
    __shared__ __align__(16) char smem[PRE_SMEM];
    const int idx = blockIdx.x;
    const int tid = threadIdx.x;

    if ((idx % 6) == 5) {
        // ---------------- bin branch ----------------
        const int bb = idx / 6;
        if (bb >= nBin) return;
        int* histL = (int*)smem;
        int* gbase = histL + MAXB;
        const int e0 = bb * EPB;

        for (int j = tid; j < NB; j += 256) histL[j] = 0;
        __syncthreads();

        #pragma unroll 8
        for (int i = 0; i < EPB / 256; ++i) {
            int e = e0 + i * 256 + tid;
            if (e < E) {
                int d = ei[E + e];
                atomicAdd(&histL[d >> BSH], 1);
            }
        }
        __syncthreads();

        for (int j = tid; j < NB; j += 256) {
            int h = histL[j];
            gbase[j] = (h > 0) ? atomicAdd(&gcnt[j], h) : 0;
            histL[j] = 0;                 // reuse as local append pos
        }
        __syncthreads();

        #pragma unroll 8
        for (int i = 0; i < EPB / 256; ++i) {
            int e = e0 + i * 256 + tid;
            if (e < E) {
                int s = ei[e];
                int d = ei[E + e];
                int b = d >> BSH;
                int pos = gbase[b] + atomicAdd(&histL[b], 1);
                if (pos < CAPB)
                    slotB[(size_t)b * CAPB + pos] =
                        ((u32)(d & (BN - 1)) << 20) | (u32)s;
            }
        }
        return;
    }

    // ---------------- node_pre branch: B = x @ W1_bot ----------------
    const int pb = idx - idx / 6;
    if (pb >= nPre) return;
    u32 (*Wch)[64] = (u32(*)[64])smem;                   // 8192 B: W1b k-pair
    u32* xs = (u32*)(smem + 8192);                       // [32][64] u32, XOR-swz

    const int node0 = pb * 64;

    // Stage W1_bot -> f16 k-pair layout (L2/L3-hot reads, coalesced).
    for (int i = tid; i < 2048; i += 256) {
        int kk = i >> 6, c = i & 63;
        float a0 = W1[(64 + 2 * kk) * 64 + c];
        float a1 = W1[(64 + 2 * kk + 1) * 64 + c];
        ((u32*)smem)[i] = f2h(a0) | (f2h(a1) << 16);
    }
    // Stage x: coalesced float4 reads; f16-pack; k-major with 16B-granule
    // XOR swizzle (writes and reads both ~2-way banked = free).
    {
        const float4* X4 = (const float4*)x;
        #pragma unroll
        for (int it = 0; it < 4; ++it) {
            int i = it * 256 + tid;            // 0..1023
            int n = i >> 4, k4 = i & 15;
            int gn = node0 + n;
            float4 v = make_float4(0.f, 0.f, 0.f, 0.f);
            if (gn < N) v = X4[(size_t)gn * 16 + k4];
            int r0 = 2 * k4, r1 = r0 + 1;
            int g = n >> 2, lo = n & 3;
            xs[r0 * 64 + (((g ^ (r0 & 15)) << 2) | lo)] = f2h(v.x) | (f2h(v.y) << 16);
            xs[r1 * 64 + (((g ^ (r1 & 15)) << 2) | lo)] = f2h(v.z) | (f2h(v.w) << 16);
        }
    }
    __syncthreads();

    const int ng = tid & 15, cg = tid >> 4;
    const int n0 = ng * 4, c0 = cg * 4;

    float acc[4][4];
    #pragma unroll
    for (int ni = 0; ni < 4; ++ni)
        #pragma unroll
        for (int ci = 0; ci < 4; ++ci) acc[ni][ci] = 0.f;

    // per kk: one b128 x read (4 nodes' k-pairs) + 1 b128 W read + 16 fdot2
    #pragma unroll 4
    for (int kk = 0; kk < 32; ++kk) {
        uint4 xq = *(const uint4*)&xs[kk * 64 + ((ng ^ (kk & 15)) << 2)];
        uint4 w = *(const uint4*)&Wch[kk][c0];
        h2 wv[4] = {u2h2(w.x), u2h2(w.y), u2h2(w.z), u2h2(w.w)};
        u32 xq4[4] = {xq.x, xq.y, xq.z, xq.w};
        #pragma unroll
        for (int ni = 0; ni < 4; ++ni) {
            h2 xh = u2h2(xq4[ni]);
            #pragma unroll
            for (int ci = 0; ci < 4; ++ci)
                acc[ni][ci] = __builtin_amdgcn_fdot2(xh, wv[ci], acc[ni][ci], false);
        }
    }

    #pragma unroll
    for (int ni = 0; ni < 4; ++ni) {
        int n = node0 + n0 + ni;
        if (n >= N) break;
        uint2 pk;
        pk.x = f2bf_rne(acc[ni][0]) | (f2bf_rne(acc[ni][1]) << 16);
        pk.y = f2bf_rne(acc[ni][2]) | (f2bf_rne(acc[ni][3]) << 16);
        *(uint2*)&Bmh[(size_t)n * 64 + c0] = pk;
    }
}

// ---------------------------------------------------------------------------
// Kernel 2: per-bucket A-GEMM (in-register) + CSR build + aggregate +
// W2 GEMM + tanh.  LDS ~26.4 KB -> 6 blocks/CU.
// ---------------------------------------------------------------------------
__device__ __forceinline__ float4 relu4add(float4 acc, float4 a, float4 b) {
    acc.x += fmaxf(a.x + b.x, 0.f);
    acc.y += fmaxf(a.y + b.y, 0.f);
    acc.z += fmaxf(a.z + b.z, 0.f);
    acc.w += fmaxf(a.w + b.w, 0.f);
    return acc;
}
__device__ __forceinline__ float4 relu4add_m(float4 acc, float4 a, float4 b, bool m) {
    acc.x += m ? fmaxf(a.x + b.x, 0.f) : 0.f;
    acc.y += m ? fmaxf(a.y + b.y, 0.f) : 0.f;
    acc.z += m ? fmaxf(a.z + b.z, 0.f) : 0.f;
    acc.w += m ? fmaxf(a.w + b.w, 0.f) : 0.f;
    return acc;
}
__device__ __forceinline__ float4 bf4(uint2 u) {
    return make_float4(bf_lo(u.x), bf_hi(u.x), bf_lo(u.y), bf_hi(u.y));
}

__global__ __launch_bounds__(256) void fused_agg(
    const float* __restrict__ x, const float* __restrict__ W1,
    const float* __restrict__ b1, const u16* __restrict__ Bmh,
    const u32* __restrict__ slotB, const int* __restrict__ gcnt,
    const float* __restrict__ W2, const float* __restrict__ b2,
    float* __restrict__ out, int N)
{
    // uni phase0: Wdh[32][64] (8K) + xs[32][64] (8K)
    // uni phase1: csrS (4K) + eStage/aggTb pool (8.7K)
    __shared__ __align__(16) char uni[16384];
    __shared__ __align__(16) u32 W2h[64][34];        // f16-packed W2, 8.7 KB
    __shared__ int histL[BN];
    __shared__ int rowO[BN + 1];
    __shared__ int ofs[BN];
    __shared__ float b2s[64];
    __shared__ float b1s[64];

    u32 (*Wdh)[64] = (u32(*)[64])uni;
    u32* xs = (u32*)(uni + 8192);
    u32* csrS = (u32*)uni;                           // [CAPB] 4KB
    u32* eStage = (u32*)(uni + 4096);                // [CAPB] (CSR build)
    uint2* aggTb = (uint2*)(uni + 4096);             // [BN][17] (agg phase)

    const int tid = threadIdx.x;
    const int b = blockIdx.x;
    const int node0 = b * BN;
    const int cntB = min(gcnt[b], CAPB);

    // ---- Stage phase0: Wdiff k-pair f16, x-tile f16 (swizzled), W2h, biases
    for (int i = tid; i < 2048; i += 256) {
        int kk = i >> 6, c = i & 63;
        int k0 = 2 * kk, k1 = k0 + 1;
        float a0 = W1[k0 * 64 + c] - W1[(64 + k0) * 64 + c];
        float a1 = W1[k1 * 64 + c] - W1[(64 + k1) * 64 + c];
        ((u32*)uni)[i] = f2h(a0) | (f2h(a1) << 16);
    }
    {
        const float4* X4 = (const float4*)x;
        #pragma unroll
        for (int it = 0; it < 4; ++it) {
            int i = it * 256 + tid;            // 0..1023
            int n = i >> 4, k4 = i & 15;
            int gn = node0 + n;
            float4 v = make_float4(0.f, 0.f, 0.f, 0.f);
            if (gn < N) v = X4[(size_t)gn * 16 + k4];
            int r0 = 2 * k4, r1 = r0 + 1;
            int g = n >> 2, lo = n & 3;
            xs[r0 * 64 + (((g ^ (r0 & 15)) << 2) | lo)] = f2h(v.x) | (f2h(v.y) << 16);
            xs[r1 * 64 + (((g ^ (r1 & 15)) << 2) | lo)] = f2h(v.z) | (f2h(v.w) << 16);
        }
    }
    for (int i = tid; i < 2048; i += 256) {
        int k = i >> 5, c2 = i & 31;
        W2h[k][c2] = f2h(W2[k * 64 + 2 * c2]) | (f2h(W2[k * 64 + 2 * c2 + 1]) << 16);
    }
    if (tid < 64) { b2s[tid] = b2[tid]; b1s[tid] = b1[tid]; }
    if (tid < BN) histL[tid] = 0;
    __syncthreads();

    // ---- A-fragment compute (registers): af[h][ci] = A[node0+ng+16h][4q+ci]
    const int q = tid & 15, ng = tid >> 4;
    const int q4 = q * 4;
    float af[4][4];
    #pragma unroll
    for (int h = 0; h < 4; ++h)
        #pragma unroll
        for (int ci = 0; ci < 4; ++ci) af[h][ci] = b1s[q4 + ci];

    #pragma unroll 4
    for (int kk = 0; kk < 32; ++kk) {
        uint4 wq = *(const uint4*)&Wdh[kk][q4];
        h2 wv[4] = {u2h2(wq.x), u2h2(wq.y), u2h2(wq.z), u2h2(wq.w)};
        #pragma unroll
        for (int h = 0; h < 4; ++h) {
            int n = ng + h * 16;
            int g = n >> 2, lo = n & 3;
            u32 xv = xs[kk * 64 + (((g ^ (kk & 15)) << 2) | lo)];
            h2 xh = u2h2(xv);
            #pragma unroll
            for (int ci = 0; ci < 4; ++ci)
                af[h][ci] = __builtin_amdgcn_fdot2(xh, wv[ci], af[h][ci], false);
        }
    }
    __syncthreads();                                 // uni phase0 dead

    // ---- CSR build ----
    for (int i = tid; i < cntB; i += 256) {
        u32 e = slotB[(size_t)b * CAPB + i];
        eStage[i] = e;
        atomicAdd(&histL[e >> 20], 1);
    }
    __syncthreads();

    if (tid < 32) {                                  // exclusive scan of 64 bins
        int l = tid;
        int h0 = histL[2 * l], h1 = histL[2 * l + 1];
        int s = h0 + h1, inc = s;
        #pragma unroll
        for (int off = 1; off < 32; off <<= 1) {
            int t = __shfl_up(inc, off);
            if (l >= off) inc += t;
        }
        int base = inc - s;
        rowO[2 * l] = base; rowO[2 * l + 1] = base + h0;
        ofs[2 * l] = base;  ofs[2 * l + 1] = base + h0;
        if (l == 31) rowO[BN] = inc;
    }
    __syncthreads();

    for (int i = tid; i < cntB; i += 256) {
        u32 e = eStage[i];
        int pos = atomicAdd(&ofs[e >> 20], 1);
        csrS[pos] = e & 0xFFFFFu;
    }
    __syncthreads();                                 // eStage dead; aggTb live

    // ---- Phase 1: gather-aggregate, 8 independent gathers per round ----
    {
        const uint2* __restrict__ B2 = (const uint2*)Bmh;
        #pragma unroll
        for (int h = 0; h < 4; ++h) {
            int nl = ng + h * 16;
            int gn = node0 + nl;
            int start = rowO[nl];
            int d = (gn < N) ? (rowO[nl + 1] - start) : 0;
            float4 a = make_float4(af[h][0], af[h][1], af[h][2], af[h][3]);
            float4 acc = make_float4(0.f, 0.f, 0.f, 0.f);

            int j = 0;
            for (; j + 8 <= d; j += 8) {             // exact 8-batches
                int ss[8];
                uint2 bb[8];
                #pragma unroll
                for (int t = 0; t < 8; ++t) ss[t] = csrS[start + j + t];
                #pragma unroll
                for (int t = 0; t < 8; ++t) bb[t] = B2[(size_t)ss[t] * 16 + q];
                #pragma unroll
                for (int t = 0; t < 8; ++t) acc = relu4add(acc, a, bf4(bb[t]));
            }
            if (j < d) {                             // masked 8-tail (clamped idx)
                int ss[8];
                uint2 bb[8];
                #pragma unroll
                for (int t = 0; t < 8; ++t) ss[t] = csrS[start + min(j + t, d - 1)];
                #pragma unroll
                for (int t = 0; t < 8; ++t) bb[t] = B2[(size_t)ss[t] * 16 + q];
                acc = relu4add(acc, a, bf4(bb[0]));
                #pragma unroll
                for (int t = 1; t < 8; ++t)
                    acc = relu4add_m(acc, a, bf4(bb[t]), j + t < d);
            }
            uint2 pk;
            pk.x = f2h(acc.x) | (f2h(acc.y) << 16);
            pk.y = f2h(acc.z) | (f2h(acc.w) << 16);
            aggTb[nl * 17 + q] = pk;
        }
    }
    __syncthreads();

    // ---- Phase 2: [64x64] @ W2 + deg*b2, tanh; W2 f16 from LDS ----
    {
        const int cg = tid & 15, g = tid >> 4;       // g: 0..15 -> 64 nodes
        const int c0 = cg * 4;
        const int nb0 = g * 4;                       // nodes nb0..nb0+3
        float o[4][4];
        #pragma unroll
        for (int ni = 0; ni < 4; ++ni) {
            float dg = (float)(rowO[nb0 + ni + 1] - rowO[nb0 + ni]);
            #pragma unroll
            for (int ci = 0; ci < 4; ++ci) o[ni][ci] = dg * b2s[c0 + ci];
        }
        #pragma unroll 2
        for (int kc = 0; kc < 16; ++kc) {
            uint2 u0 = aggTb[(nb0 + 0) * 17 + kc];
            uint2 u1 = aggTb[(nb0 + 1) * 17 + kc];
            uint2 u2 = aggTb[(nb0 + 2) * 17 + kc];
            uint2 u3 = aggTb[(nb0 + 3) * 17 + kc];
            #pragma unroll
            for (int kk = 0; kk < 4; ++kk) {
                uint2 w2p = *(const uint2*)&W2h[kc * 4 + kk][cg * 2];
                float wv[4] = {h_lo(w2p.x), h_hi(w2p.x), h_lo(w2p.y), h_hi(w2p.y)};
                float a0 = (kk < 2) ? ((kk == 0) ? h_lo(u0.x) : h_hi(u0.x))
                                    : ((kk == 2) ? h_lo(u0.y) : h_hi(u0.y));
                float a1 = (kk < 2) ? ((kk == 0) ? h_lo(u1.x) : h_hi(u1.x))
                                    : ((kk == 2) ? h_lo(u1.y) : h_hi(u1.y));
                float a2 = (kk < 2) ? ((kk == 0) ? h_lo(u2.x) : h_hi(u2.x))
                                    : ((kk == 2) ? h_lo(u2.y) : h_hi(u2.y));
                float a3 = (kk < 2) ? ((kk == 0) ? h_lo(u3.x) : h_hi(u3.x))
                                    : ((kk == 2) ? h_lo(u3.y) : h_hi(u3.y));
                #pragma unroll
                for (int ci = 0; ci < 4; ++ci) {
                    o[0][ci] += a0 * wv[ci];
                    o[1][ci] += a1 * wv[ci];
                    o[2][ci] += a2 * wv[ci];
                    o[3][ci] += a3 * wv[ci];
                }
            }
        }
        #pragma unroll
        for (int ni = 0; ni < 4; ++ni) {
            int gn = node0 + nb0 + ni;
            if (gn < N) {
                float4 r = make_float4(tanhf(o[ni][0]), tanhf(o[ni][1]),
                                       tanhf(o[ni][2]), tanhf(o[ni][3]));
                ((float4*)out)[(size_t)gn * 16 + cg] = r;
            }
        }
    }
}

// ---------------------------------------------------------------------------
extern "C" void kernel_launch(void* const* d_in, const int* in_sizes, int n_in,
                              void* d_out, int out_size, void* d_ws, size_t ws_size,
                              hipStream_t stream)
{
    const float* x  = (const float*)d_in[0];
    const int*   ei = (const int*)d_in[1];     // [2,E]: row0=src, row1=dst
    const float* W1 = (const float*)d_in[2];   // [128,64]
    const float* b1 = (const float*)d_in[3];   // [64]
    const float* W2 = (const float*)d_in[4];   // [64,64]
    const float* b2 = (const float*)d_in[5];   // [64]
    float* out = (float*)d_out;

    const int N = in_sizes[0] / FDIM;          // 100000
    const int E = in_sizes[1] / 2;             // 1200000
    const int NB = (N + BN - 1) / BN;          // 1563 buckets

    // Workspace (re-poisoned 0xAA every call; gcnt zeroed below):
    u16*   Bmh   = (u16*)d_ws;                          // N*64 bf16 = 12.8 MB
    u32*   slotB = (u32*)(Bmh + (size_t)N * FDIM);      // NB*CAPB u32 = 6.4 MB
    int*   gcnt  = (int*)(slotB + (size_t)NB * CAPB);   // NB i32

    hipMemsetAsync(gcnt, 0, (size_t)NB * sizeof(int), stream);

    // Interleaved heterogeneous grid: 1 bin block per 6 (idx%6==5), rest pre.
    const int nPre = (N + 63) / 64;            // 1563
    const int nBin = (E + EPB - 1) / EPB;      // 293
    int T = (nPre * 6 + 4) / 5;
    while (T - T / 6 < nPre) ++T;
    if (T < 6 * nBin) T = 6 * nBin;

    prep_k<<<T, 256, 0, stream>>>(x, W1, Bmh, ei, slotB, gcnt,
                                  N, E, NB, nPre, nBin);
    fused_agg<<<NB, 256, 0, stream>>>(x, W1, b1, Bmh, slotB, gcnt, W2, b2, out, N);
}

// Round 7
// 171.041 us; speedup vs baseline: 1.1293x; 1.0851x over previous
//
#include <hip/hip_runtime.h>
#include <math.h>

// EdgeConv, factorized:
//   A[i] = x[i] @ (W1_top - W1_bot) + b1        (computed in fused_agg, f32 regs)
//   B[j] = x[j] @ W1_bot                        (64-dim f16, per node, prep_k)
//   agg1[i] = sum_{e: dst=i} relu(A[i] + B[src_e])
//   out[i]  = tanh(agg1[i] @ W2 + deg_i * b2)
//
// R16 -> R17: fused_agg was serialized on per-thread VALU inst count
// (~3600/thread; added A-GEMM cost 3.4x its throughput time -> dependency-
// limited).  Cut it with packed f16 math: B stored f16 (better precision
// than bf16 AND enables pk ops); gather = v_pk_add_f16 + v_pk_max_f16 +
// 2x v_dot2_f32_f16 per pair (16->8 VALU/edge, exact f32 accumulate);
// phase-2 W2 GEMM via fdot2 on k-pair-packed W2 (~1850->~640 inst);
// A-GEMM reads xs b128 (4 consecutive nodes/thread).  ~2300 inst/thread.

#define FDIM 64
#define BN 64             // nodes per bucket (bin/agg granularity)
#define BSH 6             // log2(BN)
#define CAPB 1024         // bucket capacity (mean 768, +9 sigma)
#define MAXB 2048         // LDS bucket-counter array bound in bin branch
#define EPB 4096          // edges per bin block
#define PRE_SMEM 16384    // bytes: Wch 8192 + xs 8192  (== bin 16384)

typedef unsigned int u32;
typedef unsigned short u16;
typedef _Float16 hf;
typedef _Float16 h2 __attribute__((ext_vector_type(2)));

__device__ __forceinline__ u32 f2h(float f) {
    union { u16 s; hf h; } c; c.h = (hf)f; return (u32)c.s;
}
__device__ __forceinline__ h2 u2h2(u32 u) {
    union { u32 u; h2 h; } c; c.u = u; return c.h;
}

// ---------------------------------------------------------------------------
// Kernel 1: merged prep.  blockIdx%6==5 -> bin branch, else node_pre
// (B-GEMM only: 64 nodes x 64 cols, f16 output).
// ---------------------------------------------------------------------------
__global__ __launch_bounds__(256) void prep_k(
    const float* __restrict__ x, const float* __restrict__ W1,
    u16* __restrict__ Bmh, const int* __restrict__ ei,
    u32* __restrict__ slotB, int* __restrict__ gcnt,
    int N, int E, int NB, int nPre, int nBin)
{
    __shared__ __align__(16) char smem[PRE_SMEM];
    const int idx = blockIdx.x;
    const int tid = threadIdx.x;

    if ((idx % 6) == 5) {
        // ---------------- bin branch ----------------
        const int bb = idx / 6;
        if (bb >= nBin) return;
        int* histL = (int*)smem;
        int* gbase = histL + MAXB;
        const int e0 = bb * EPB;

        for (int j = tid; j < NB; j += 256) histL[j] = 0;
        __syncthreads();

        #pragma unroll 8
        for (int i = 0; i < EPB / 256; ++i) {
            int e = e0 + i * 256 + tid;
            if (e < E) {
                int d = ei[E + e];
                atomicAdd(&histL[d >> BSH], 1);
            }
        }
        __syncthreads();

        for (int j = tid; j < NB; j += 256) {
            int h = histL[j];
            gbase[j] = (h > 0) ? atomicAdd(&gcnt[j], h) : 0;
            histL[j] = 0;                 // reuse as local append pos
        }
        __syncthreads();

        #pragma unroll 8
        for (int i = 0; i < EPB / 256; ++i) {
            int e = e0 + i * 256 + tid;
            if (e < E) {
                int s = ei[e];
                int d = ei[E + e];
                int b = d >> BSH;
                int pos = gbase[b] + atomicAdd(&histL[b], 1);
                if (pos < CAPB)
                    slotB[(size_t)b * CAPB + pos] =
                        ((u32)(d & (BN - 1)) << 20) | (u32)s;
            }
        }
        return;
    }

    // ---------------- node_pre branch: B = x @ W1_bot ----------------
    const int pb = idx - idx / 6;
    if (pb >= nPre) return;
    u32 (*Wch)[64] = (u32(*)[64])smem;                   // 8192 B: W1b k-pair
    u32* xs = (u32*)(smem + 8192);                       // [32][64] u32, XOR-swz

    const int node0 = pb * 64;

    // Stage W1_bot -> f16 k-pair layout (L2/L3-hot reads, coalesced).
    for (int i = tid; i < 2048; i += 256) {
        int kk = i >> 6, c = i & 63;
        float a0 = W1[(64 + 2 * kk) * 64 + c];
        float a1 = W1[(64 + 2 * kk + 1) * 64 + c];
        ((u32*)smem)[i] = f2h(a0) | (f2h(a1) << 16);
    }
    // Stage x: coalesced float4 reads; f16-pack; k-major with 16B-granule
    // XOR swizzle (writes and reads both ~2-way banked = free).
    {
        const float4* X4 = (const float4*)x;
        #pragma unroll
        for (int it = 0; it < 4; ++it) {
            int i = it * 256 + tid;            // 0..1023
            int n = i >> 4, k4 = i & 15;
            int gn = node0 + n;
            float4 v = make_float4(0.f, 0.f, 0.f, 0.f);
            if (gn < N) v = X4[(size_t)gn * 16 + k4];
            int r0 = 2 * k4, r1 = r0 + 1;
            int g = n >> 2, lo = n & 3;
            xs[r0 * 64 + (((g ^ (r0 & 15)) << 2) | lo)] = f2h(v.x) | (f2h(v.y) << 16);
            xs[r1 * 64 + (((g ^ (r1 & 15)) << 2) | lo)] = f2h(v.z) | (f2h(v.w) << 16);
        }
    }
    __syncthreads();

    const int ng = tid & 15, cg = tid >> 4;
    const int n0 = ng * 4, c0 = cg * 4;

    float acc[4][4];
    #pragma unroll
    for (int ni = 0; ni < 4; ++ni)
        #pragma unroll
        for (int ci = 0; ci < 4; ++ci) acc[ni][ci] = 0.f;

    // per kk: one b128 x read (4 nodes' k-pairs) + 1 b128 W read + 16 fdot2
    #pragma unroll 4
    for (int kk = 0; kk < 32; ++kk) {
        uint4 xq = *(const uint4*)&xs[kk * 64 + ((ng ^ (kk & 15)) << 2)];
        uint4 w = *(const uint4*)&Wch[kk][c0];
        h2 wv[4] = {u2h2(w.x), u2h2(w.y), u2h2(w.z), u2h2(w.w)};
        u32 xq4[4] = {xq.x, xq.y, xq.z, xq.w};
        #pragma unroll
        for (int ni = 0; ni < 4; ++ni) {
            h2 xh = u2h2(xq4[ni]);
            #pragma unroll
            for (int ci = 0; ci < 4; ++ci)
                acc[ni][ci] = __builtin_amdgcn_fdot2(xh, wv[ci], acc[ni][ci], false);
        }
    }

    #pragma unroll
    for (int ni = 0; ni < 4; ++ni) {
        int n = node0 + n0 + ni;
        if (n >= N) break;
        uint2 pk;
        pk.x = f2h(acc[ni][0]) | (f2h(acc[ni][1]) << 16);
        pk.y = f2h(acc[ni][2]) | (f2h(acc[ni][3]) << 16);
        *(uint2*)&Bmh[(size_t)n * 64 + c0] = pk;
    }
}

// ---------------------------------------------------------------------------
// Kernel 2: per-bucket A-GEMM (in-register) + CSR build + packed-f16
// gather-aggregate + fdot2 W2 GEMM + tanh.  LDS ~25.9 KB -> 6 blocks/CU.
// ---------------------------------------------------------------------------
__global__ __launch_bounds__(256) void fused_agg(
    const float* __restrict__ x, const float* __restrict__ W1,
    const float* __restrict__ b1, const u16* __restrict__ Bmh,
    const u32* __restrict__ slotB, const int* __restrict__ gcnt,
    const float* __restrict__ W2, const float* __restrict__ b2,
    float* __restrict__ out, int N)
{
    // uni phase0: Wdh[32][64] (8K) + xs[32][64] (8K)
    // uni phase1: csrS (4K) + eStage/aggTb pool (8.7K)
    __shared__ __align__(16) char uni[16384];
    __shared__ __align__(16) u32 W2kp[2048];         // k-pair-packed f16 W2, 8 KB
    __shared__ int histL[BN];
    __shared__ int rowO[BN + 1];
    __shared__ int ofs[BN];
    __shared__ float b2s[64];
    __shared__ float b1s[64];

    u32 (*Wdh)[64] = (u32(*)[64])uni;
    u32* xs = (u32*)(uni + 8192);
    u32* csrS = (u32*)uni;                           // [CAPB] 4KB
    u32* eStage = (u32*)(uni + 4096);                // [CAPB] (CSR build)
    uint2* aggTb = (uint2*)(uni + 4096);             // [BN][17] (agg phase)

    const int tid = threadIdx.x;
    const int b = blockIdx.x;
    const int node0 = b * BN;
    const int cntB = min(gcnt[b], CAPB);

    // ---- Stage phase0: Wdiff k-pair f16, x-tile f16 (swizzled), W2kp, biases
    for (int i = tid; i < 2048; i += 256) {
        int kk = i >> 6, c = i & 63;
        int k0 = 2 * kk, k1 = k0 + 1;
        float a0 = W1[k0 * 64 + c] - W1[(64 + k0) * 64 + c];
        float a1 = W1[k1 * 64 + c] - W1[(64 + k1) * 64 + c];
        ((u32*)uni)[i] = f2h(a0) | (f2h(a1) << 16);
    }
    {
        const float4* X4 = (const float4*)x;
        #pragma unroll
        for (int it = 0; it < 4; ++it) {
            int i = it * 256 + tid;            // 0..1023
            int n = i >> 4, k4 = i & 15;
            int gn = node0 + n;
            float4 v = make_float4(0.f, 0.f, 0.f, 0.f);
            if (gn < N) v = X4[(size_t)gn * 16 + k4];
            int r0 = 2 * k4, r1 = r0 + 1;
            int g = n >> 2, lo = n & 3;
            xs[r0 * 64 + (((g ^ (r0 & 15)) << 2) | lo)] = f2h(v.x) | (f2h(v.y) << 16);
            xs[r1 * 64 + (((g ^ (r1 & 15)) << 2) | lo)] = f2h(v.z) | (f2h(v.w) << 16);
        }
    }
    // W2kp[kk*64+c] = ( f16(W2[2kk][c]), f16(W2[2kk+1][c]) )
    for (int i = tid; i < 2048; i += 256) {
        int kk = i >> 6, c = i & 63;
        W2kp[i] = f2h(W2[(2 * kk) * 64 + c]) | (f2h(W2[(2 * kk + 1) * 64 + c]) << 16);
    }
    if (tid < 64) { b2s[tid] = b2[tid]; b1s[tid] = b1[tid]; }
    if (tid < BN) histL[tid] = 0;
    __syncthreads();

    // ---- A-fragment compute (registers): af[h][ci] = A[node0+4*ng+h][4q+ci]
    const int q = tid & 15, ng = tid >> 4;
    const int q4 = q * 4;
    float af[4][4];
    #pragma unroll
    for (int h = 0; h < 4; ++h)
        #pragma unroll
        for (int ci = 0; ci < 4; ++ci) af[h][ci] = b1s[q4 + ci];

    #pragma unroll 4
    for (int kk = 0; kk < 32; ++kk) {
        uint4 xq = *(const uint4*)&xs[kk * 64 + ((ng ^ (kk & 15)) << 2)];
        uint4 wq = *(const uint4*)&Wdh[kk][q4];
        h2 wv[4] = {u2h2(wq.x), u2h2(wq.y), u2h2(wq.z), u2h2(wq.w)};
        u32 xq4[4] = {xq.x, xq.y, xq.z, xq.w};
        #pragma unroll
        for (int h = 0; h < 4; ++h) {
            h2 xh = u2h2(xq4[h]);
            #pragma unroll
            for (int ci = 0; ci < 4; ++ci)
                af[h][ci] = __builtin_amdgcn_fdot2(xh, wv[ci], af[h][ci], false);
        }
    }
    // Pack A to f16 pairs for the packed gather.
    u32 pa[4][2];
    #pragma unroll
    for (int h = 0; h < 4; ++h) {
        pa[h][0] = f2h(af[h][0]) | (f2h(af[h][1]) << 16);
        pa[h][1] = f2h(af[h][2]) | (f2h(af[h][3]) << 16);
    }
    __syncthreads();                                 // uni phase0 dead

    // ---- CSR build ----
    for (int i = tid; i < cntB; i += 256) {
        u32 e = slotB[(size_t)b * CAPB + i];
        eStage[i] = e;
        atomicAdd(&histL[e >> 20], 1);
    }
    __syncthreads();

    if (tid < 32) {                                  // exclusive scan of 64 bins
        int l = tid;
        int h0 = histL[2 * l], h1 = histL[2 * l + 1];
        int s = h0 + h1, inc = s;
        #pragma unroll
        for (int off = 1; off < 32; off <<= 1) {
            int t = __shfl_up(inc, off);
            if (l >= off) inc += t;
        }
        int base = inc - s;
        rowO[2 * l] = base; rowO[2 * l + 1] = base + h0;
        ofs[2 * l] = base;  ofs[2 * l + 1] = base + h0;
        if (l == 31) rowO[BN] = inc;
    }
    __syncthreads();

    for (int i = tid; i < cntB; i += 256) {
        u32 e = eStage[i];
        int pos = atomicAdd(&ofs[e >> 20], 1);
        csrS[pos] = e & 0xFFFFFu;
    }
    __syncthreads();                                 // eStage dead; aggTb live

    // ---- Phase 1: packed-f16 gather-aggregate ----
    {
        const uint2* __restrict__ B2 = (const uint2*)Bmh;
        const h2 SEL10 = {(_Float16)1.f, (_Float16)0.f};
        const h2 SEL01 = {(_Float16)0.f, (_Float16)1.f};
        const h2 HZ = {(_Float16)0.f, (_Float16)0.f};
        #pragma unroll
        for (int h = 0; h < 4; ++h) {
            int nl = ng * 4 + h;
            int gn = node0 + nl;
            int start = rowO[nl];
            int d = (gn < N) ? (rowO[nl + 1] - start) : 0;
            h2 A0 = u2h2(pa[h][0]), A1 = u2h2(pa[h][1]);
            float ac0 = 0.f, ac1 = 0.f, ac2 = 0.f, ac3 = 0.f;

            int j = 0;
            for (; j + 8 <= d; j += 8) {             // exact 8-batches
                int ss[8];
                uint2 bb[8];
                #pragma unroll
                for (int t = 0; t < 8; ++t) ss[t] = csrS[start + j + t];
                #pragma unroll
                for (int t = 0; t < 8; ++t) bb[t] = B2[(size_t)ss[t] * 16 + q];
                #pragma unroll
                for (int t = 0; t < 8; ++t) {
                    h2 t0 = A0 + u2h2(bb[t].x);
                    h2 t1 = A1 + u2h2(bb[t].y);
                    t0 = __builtin_elementwise_max(t0, HZ);
                    t1 = __builtin_elementwise_max(t1, HZ);
                    ac0 = __builtin_amdgcn_fdot2(t0, SEL10, ac0, false);
                    ac1 = __builtin_amdgcn_fdot2(t0, SEL01, ac1, false);
                    ac2 = __builtin_amdgcn_fdot2(t1, SEL10, ac2, false);
                    ac3 = __builtin_amdgcn_fdot2(t1, SEL01, ac3, false);
                }
            }
            if (j < d) {                             // masked 8-tail: -inf -> relu 0
                int ss[8];
                uint2 bb[8];
                #pragma unroll
                for (int t = 0; t < 8; ++t) ss[t] = csrS[start + min(j + t, d - 1)];
                #pragma unroll
                for (int t = 0; t < 8; ++t) bb[t] = B2[(size_t)ss[t] * 16 + q];
                #pragma unroll
                for (int t = 0; t < 8; ++t) {
                    if (j + t >= d) { bb[t].x = 0xFC00FC00u; bb[t].y = 0xFC00FC00u; }
                    h2 t0 = A0 + u2h2(bb[t].x);
                    h2 t1 = A1 + u2h2(bb[t].y);
                    t0 = __builtin_elementwise_max(t0, HZ);
                    t1 = __builtin_elementwise_max(t1, HZ);
                    ac0 = __builtin_amdgcn_fdot2(t0, SEL10, ac0, false);
                    ac1 = __builtin_amdgcn_fdot2(t0, SEL01, ac1, false);
                    ac2 = __builtin_amdgcn_fdot2(t1, SEL10, ac2, false);
                    ac3 = __builtin_amdgcn_fdot2(t1, SEL01, ac3, false);
                }
            }
            uint2 pk;
            pk.x = f2h(ac0) | (f2h(ac1) << 16);
            pk.y = f2h(ac2) | (f2h(ac3) << 16);
            aggTb[nl * 17 + q] = pk;
        }
    }
    __syncthreads();

    // ---- Phase 2: [64x64] @ W2 via fdot2 + deg*b2, tanh ----
    {
        const int cg = tid & 15, g = tid >> 4;       // g: 0..15 -> 64 nodes
        const int c0 = cg * 4;
        const int nb0 = g * 4;                       // nodes nb0..nb0+3
        float o[4][4];
        #pragma unroll
        for (int ni = 0; ni < 4; ++ni) {
            float dg = (float)(rowO[nb0 + ni + 1] - rowO[nb0 + ni]);
            #pragma unroll
            for (int ci = 0; ci < 4; ++ci) o[ni][ci] = dg * b2s[c0 + ci];
        }
        #pragma unroll 4
        for (int kc = 0; kc < 16; ++kc) {
            uint2 u0 = aggTb[(nb0 + 0) * 17 + kc];
            uint2 u1 = aggTb[(nb0 + 1) * 17 + kc];
            uint2 u2 = aggTb[(nb0 + 2) * 17 + kc];
            uint2 u3 = aggTb[(nb0 + 3) * 17 + kc];
            uint4 wA = *(const uint4*)&W2kp[(2 * kc) * 64 + c0];
            uint4 wB = *(const uint4*)&W2kp[(2 * kc + 1) * 64 + c0];
            h2 wa[4] = {u2h2(wA.x), u2h2(wA.y), u2h2(wA.z), u2h2(wA.w)};
            h2 wb[4] = {u2h2(wB.x), u2h2(wB.y), u2h2(wB.z), u2h2(wB.w)};
            h2 a0x = u2h2(u0.x), a0y = u2h2(u0.y);
            h2 a1x = u2h2(u1.x), a1y = u2h2(u1.y);
            h2 a2x = u2h2(u2.x), a2y = u2h2(u2.y);
            h2 a3x = u2h2(u3.x), a3y = u2h2(u3.y);
            #pragma unroll
            for (int ci = 0; ci < 4; ++ci) {
                o[0][ci] = __builtin_amdgcn_fdot2(a0x, wa[ci], o[0][ci], false);
                o[0][ci] = __builtin_amdgcn_fdot2(a0y, wb[ci], o[0][ci], false);
                o[1][ci] = __builtin_amdgcn_fdot2(a1x, wa[ci], o[1][ci], false);
                o[1][ci] = __builtin_amdgcn_fdot2(a1y, wb[ci], o[1][ci], false);
                o[2][ci] = __builtin_amdgcn_fdot2(a2x, wa[ci], o[2][ci], false);
                o[2][ci] = __builtin_amdgcn_fdot2(a2y, wb[ci], o[2][ci], false);
                o[3][ci] = __builtin_amdgcn_fdot2(a3x, wa[ci], o[3][ci], false);
                o[3][ci] = __builtin_amdgcn_fdot2(a3y, wb[ci], o[3][ci], false);
            }
        }
        #pragma unroll
        for (int ni = 0; ni < 4; ++ni) {
            int gn = node0 + nb0 + ni;
            if (gn < N) {
                float4 r = make_float4(tanhf(o[ni][0]), tanhf(o[ni][1]),
                                       tanhf(o[ni][2]), tanhf(o[ni][3]));
                ((float4*)out)[(size_t)gn * 16 + cg] = r;
            }
        }
    }
}

// ---------------------------------------------------------------------------
extern "C" void kernel_launch(void* const* d_in, const int* in_sizes, int n_in,
                              void* d_out, int out_size, void* d_ws, size_t ws_size,
                              hipStream_t stream)
{
    const float* x  = (const float*)d_in[0];
    const int*   ei = (const int*)d_in[1];     // [2,E]: row0=src, row1=dst
    const float* W1 = (const float*)d_in[2];   // [128,64]
    const float* b1 = (const float*)d_in[3];   // [64]
    const float* W2 = (const float*)d_in[4];   // [64,64]
    const float* b2 = (const float*)d_in[5];   // [64]
    float* out = (float*)d_out;

    const int N = in_sizes[0] / FDIM;          // 100000
    const int E = in_sizes[1] / 2;             // 1200000
    const int NB = (N + BN - 1) / BN;          // 1563 buckets

    // Workspace (re-poisoned 0xAA every call; gcnt zeroed below):
    u16*   Bmh   = (u16*)d_ws;                          // N*64 f16 = 12.8 MB
    u32*   slotB = (u32*)(Bmh + (size_t)N * FDIM);      // NB*CAPB u32 = 6.4 MB
    int*   gcnt  = (int*)(slotB + (size_t)NB * CAPB);   // NB i32

    hipMemsetAsync(gcnt, 0, (size_t)NB * sizeof(int), stream);

    // Interleaved heterogeneous grid: 1 bin block per 6 (idx%6==5), rest pre.
    const int nPre = (N + 63) / 64;            // 1563
    const int nBin = (E + EPB - 1) / EPB;      // 293
    int T = (nPre * 6 + 4) / 5;
    while (T - T / 6 < nPre) ++T;
    if (T < 6 * nBin) T = 6 * nBin;

    prep_k<<<T, 256, 0, stream>>>(x, W1, Bmh, ei, slotB, gcnt,
                                  N, E, NB, nPre, nBin);
    fused_agg<<<NB, 256, 0, stream>>>(x, W1, b1, Bmh, slotB, gcnt, W2, b2, out, N);
}

// Round 8
// 169.665 us; speedup vs baseline: 1.1384x; 1.0081x over previous
//
#include <hip/hip_runtime.h>
#include <math.h>

// EdgeConv, factorized:
//   A[i] = x[i] @ (W1_top - W1_bot) + b1        (computed in fused_agg, f32 regs)
//   B[j] = x[j] @ W1_bot                        (64-dim f16, per node, prep_k)
//   agg1[i] = sum_{e: dst=i} relu(A[i] + B[src_e])
//   out[i]  = tanh(agg1[i] @ W2 + deg_i * b2)
//
// R17 -> R18: fused_agg still latency-bound (Occ 38%, HBM 21%, VALU 53%).
// LDS 26.1 KB capped residency at 6 blocks/CU.  W2kp (8 KB) was staged in
// phase 0 but only read in phase 2 -- now overlaid into the unified buffer
// and staged AFTER the gather (over dead csrS/eStage): LDS ~18 KB -> 8
// blocks/CU (+33% waves).  uni layout: phase0 Wdh[0,8K)+xs[8K,16K);
// CSR csrS[8.5K,12.5K)+eStage[12.5K,16.5K); gather writes aggTb[0,8.5K);
// phase2 aggTb[0,8.5K)+W2kp[8.5K,16.5K).  No other logic changes.

#define FDIM 64
#define BN 64             // nodes per bucket (bin/agg granularity)
#define BSH 6             // log2(BN)
#define CAPB 1024         // bucket capacity (mean 768, +9 sigma)
#define MAXB 2048         // LDS bucket-counter array bound in bin branch
#define EPB 4096          // edges per bin block
#define PRE_SMEM 16384    // bytes: Wch 8192 + xs 8192  (== bin 16384)

typedef unsigned int u32;
typedef unsigned short u16;
typedef _Float16 hf;
typedef _Float16 h2 __attribute__((ext_vector_type(2)));

__device__ __forceinline__ u32 f2h(float f) {
    union { u16 s; hf h; } c; c.h = (hf)f; return (u32)c.s;
}
__device__ __forceinline__ h2 u2h2(u32 u) {
    union { u32 u; h2 h; } c; c.u = u; return c.h;
}

// ---------------------------------------------------------------------------
// Kernel 1: merged prep.  blockIdx%6==5 -> bin branch, else node_pre
// (B-GEMM only: 64 nodes x 64 cols, f16 output).
// ---------------------------------------------------------------------------
__global__ __launch_bounds__(256) void prep_k(
    const float* __restrict__ x, const float* __restrict__ W1,
    u16* __restrict__ Bmh, const int* __restrict__ ei,
    u32* __restrict__ slotB, int* __restrict__ gcnt,
    int N, int E, int NB, int nPre, int nBin)
{
    __shared__ __align__(16) char smem[PRE_SMEM];
    const int idx = blockIdx.x;
    const int tid = threadIdx.x;

    if ((idx % 6) == 5) {
        // ---------------- bin branch ----------------
        const int bb = idx / 6;
        if (bb >= nBin) return;
        int* histL = (int*)smem;
        int* gbase = histL + MAXB;
        const int e0 = bb * EPB;

        for (int j = tid; j < NB; j += 256) histL[j] = 0;
        __syncthreads();

        #pragma unroll 8
        for (int i = 0; i < EPB / 256; ++i) {
            int e = e0 + i * 256 + tid;
            if (e < E) {
                int d = ei[E + e];
                atomicAdd(&histL[d >> BSH], 1);
            }
        }
        __syncthreads();

        for (int j = tid; j < NB; j += 256) {
            int h = histL[j];
            gbase[j] = (h > 0) ? atomicAdd(&gcnt[j], h) : 0;
            histL[j] = 0;                 // reuse as local append pos
        }
        __syncthreads();

        #pragma unroll 8
        for (int i = 0; i < EPB / 256; ++i) {
            int e = e0 + i * 256 + tid;
            if (e < E) {
                int s = ei[e];
                int d = ei[E + e];
                int b = d >> BSH;
                int pos = gbase[b] + atomicAdd(&histL[b], 1);
                if (pos < CAPB)
                    slotB[(size_t)b * CAPB + pos] =
                        ((u32)(d & (BN - 1)) << 20) | (u32)s;
            }
        }
        return;
    }

    // ---------------- node_pre branch: B = x @ W1_bot ----------------
    const int pb = idx - idx / 6;
    if (pb >= nPre) return;
    u32 (*Wch)[64] = (u32(*)[64])smem;                   // 8192 B: W1b k-pair
    u32* xs = (u32*)(smem + 8192);                       // [32][64] u32, XOR-swz

    const int node0 = pb * 64;

    // Stage W1_bot -> f16 k-pair layout (L2/L3-hot reads, coalesced).
    for (int i = tid; i < 2048; i += 256) {
        int kk = i >> 6, c = i & 63;
        float a0 = W1[(64 + 2 * kk) * 64 + c];
        float a1 = W1[(64 + 2 * kk + 1) * 64 + c];
        ((u32*)smem)[i] = f2h(a0) | (f2h(a1) << 16);
    }
    // Stage x: coalesced float4 reads; f16-pack; k-major with 16B-granule
    // XOR swizzle (writes and reads both ~2-way banked = free).
    {
        const float4* X4 = (const float4*)x;
        #pragma unroll
        for (int it = 0; it < 4; ++it) {
            int i = it * 256 + tid;            // 0..1023
            int n = i >> 4, k4 = i & 15;
            int gn = node0 + n;
            float4 v = make_float4(0.f, 0.f, 0.f, 0.f);
            if (gn < N) v = X4[(size_t)gn * 16 + k4];
            int r0 = 2 * k4, r1 = r0 + 1;
            int g = n >> 2, lo = n & 3;
            xs[r0 * 64 + (((g ^ (r0 & 15)) << 2) | lo)] = f2h(v.x) | (f2h(v.y) << 16);
            xs[r1 * 64 + (((g ^ (r1 & 15)) << 2) | lo)] = f2h(v.z) | (f2h(v.w) << 16);
        }
    }
    __syncthreads();

    const int ng = tid & 15, cg = tid >> 4;
    const int n0 = ng * 4, c0 = cg * 4;

    float acc[4][4];
    #pragma unroll
    for (int ni = 0; ni < 4; ++ni)
        #pragma unroll
        for (int ci = 0; ci < 4; ++ci) acc[ni][ci] = 0.f;

    // per kk: one b128 x read (4 nodes' k-pairs) + 1 b128 W read + 16 fdot2
    #pragma unroll 4
    for (int kk = 0; kk < 32; ++kk) {
        uint4 xq = *(const uint4*)&xs[kk * 64 + ((ng ^ (kk & 15)) << 2)];
        uint4 w = *(const uint4*)&Wch[kk][c0];
        h2 wv[4] = {u2h2(w.x), u2h2(w.y), u2h2(w.z), u2h2(w.w)};
        u32 xq4[4] = {xq.x, xq.y, xq.z, xq.w};
        #pragma unroll
        for (int ni = 0; ni < 4; ++ni) {
            h2 xh = u2h2(xq4[ni]);
            #pragma unroll
            for (int ci = 0; ci < 4; ++ci)
                acc[ni][ci] = __builtin_amdgcn_fdot2(xh, wv[ci], acc[ni][ci], false);
        }
    }

    #pragma unroll
    for (int ni = 0; ni < 4; ++ni) {
        int n = node0 + n0 + ni;
        if (n >= N) break;
        uint2 pk;
        pk.x = f2h(acc[ni][0]) | (f2h(acc[ni][1]) << 16);
        pk.y = f2h(acc[ni][2]) | (f2h(acc[ni][3]) << 16);
        *(uint2*)&Bmh[(size_t)n * 64 + c0] = pk;
    }
}

// ---------------------------------------------------------------------------
// Kernel 2: per-bucket A-GEMM (in-register) + CSR build + packed-f16
// gather-aggregate + fdot2 W2 GEMM + tanh.
// LDS ~18 KB -> 8 blocks/CU (unified buffer, W2kp staged post-gather).
// ---------------------------------------------------------------------------
__global__ __launch_bounds__(256) void fused_agg(
    const float* __restrict__ x, const float* __restrict__ W1,
    const float* __restrict__ b1, const u16* __restrict__ Bmh,
    const u32* __restrict__ slotB, const int* __restrict__ gcnt,
    const float* __restrict__ W2, const float* __restrict__ b2,
    float* __restrict__ out, int N)
{
    // Unified buffer, phase overlays:
    //   phase0 (stage+A-GEMM):  Wdh [0,8192)      xs [8192,16384)
    //   CSR build:              csrS [8704,12800)  eStage [12800,16896)
    //   gather:                 csrS read          aggTb [0,8704) write
    //   phase2:                 aggTb [0,8704)     W2kp [8704,16896)
    __shared__ __align__(16) char uni[16896];
    __shared__ int histL[BN];
    __shared__ int rowO[BN + 1];
    __shared__ int ofs[BN];
    __shared__ float b2s[64];
    __shared__ float b1s[64];

    u32 (*Wdh)[64] = (u32(*)[64])uni;
    u32* xs = (u32*)(uni + 8192);
    uint2* aggTb = (uint2*)uni;                      // [BN][17]
    u32* csrS = (u32*)(uni + 8704);                  // [CAPB] 4KB
    u32* eStage = (u32*)(uni + 12800);               // [CAPB] 4KB
    u32* W2kp = (u32*)(uni + 8704);                  // [2048] 8KB (phase2)

    const int tid = threadIdx.x;
    const int b = blockIdx.x;
    const int node0 = b * BN;
    const int cntB = min(gcnt[b], CAPB);

    // ---- Stage phase0: Wdiff k-pair f16, x-tile f16 (swizzled), biases
    for (int i = tid; i < 2048; i += 256) {
        int kk = i >> 6, c = i & 63;
        int k0 = 2 * kk, k1 = k0 + 1;
        float a0 = W1[k0 * 64 + c] - W1[(64 + k0) * 64 + c];
        float a1 = W1[k1 * 64 + c] - W1[(64 + k1) * 64 + c];
        ((u32*)uni)[i] = f2h(a0) | (f2h(a1) << 16);
    }
    {
        const float4* X4 = (const float4*)x;
        #pragma unroll
        for (int it = 0; it < 4; ++it) {
            int i = it * 256 + tid;            // 0..1023
            int n = i >> 4, k4 = i & 15;
            int gn = node0 + n;
            float4 v = make_float4(0.f, 0.f, 0.f, 0.f);
            if (gn < N) v = X4[(size_t)gn * 16 + k4];
            int r0 = 2 * k4, r1 = r0 + 1;
            int g = n >> 2, lo = n & 3;
            xs[r0 * 64 + (((g ^ (r0 & 15)) << 2) | lo)] = f2h(v.x) | (f2h(v.y) << 16);
            xs[r1 * 64 + (((g ^ (r1 & 15)) << 2) | lo)] = f2h(v.z) | (f2h(v.w) << 16);
        }
    }
    if (tid < 64) { b2s[tid] = b2[tid]; b1s[tid] = b1[tid]; }
    if (tid < BN) histL[tid] = 0;
    __syncthreads();

    // ---- A-fragment compute (registers): af[h][ci] = A[node0+4*ng+h][4q+ci]
    const int q = tid & 15, ng = tid >> 4;
    const int q4 = q * 4;
    float af[4][4];
    #pragma unroll
    for (int h = 0; h < 4; ++h)
        #pragma unroll
        for (int ci = 0; ci < 4; ++ci) af[h][ci] = b1s[q4 + ci];

    #pragma unroll 4
    for (int kk = 0; kk < 32; ++kk) {
        uint4 xq = *(const uint4*)&xs[kk * 64 + ((ng ^ (kk & 15)) << 2)];
        uint4 wq = *(const uint4*)&Wdh[kk][q4];
        h2 wv[4] = {u2h2(wq.x), u2h2(wq.y), u2h2(wq.z), u2h2(wq.w)};
        u32 xq4[4] = {xq.x, xq.y, xq.z, xq.w};
        #pragma unroll
        for (int h = 0; h < 4; ++h) {
            h2 xh = u2h2(xq4[h]);
            #pragma unroll
            for (int ci = 0; ci < 4; ++ci)
                af[h][ci] = __builtin_amdgcn_fdot2(xh, wv[ci], af[h][ci], false);
        }
    }
    // Pack A to f16 pairs for the packed gather.
    u32 pa[4][2];
    #pragma unroll
    for (int h = 0; h < 4; ++h) {
        pa[h][0] = f2h(af[h][0]) | (f2h(af[h][1]) << 16);
        pa[h][1] = f2h(af[h][2]) | (f2h(af[h][3]) << 16);
    }
    __syncthreads();                                 // phase0 buffers dead

    // ---- CSR build ----
    for (int i = tid; i < cntB; i += 256) {
        u32 e = slotB[(size_t)b * CAPB + i];
        eStage[i] = e;
        atomicAdd(&histL[e >> 20], 1);
    }
    __syncthreads();

    if (tid < 32) {                                  // exclusive scan of 64 bins
        int l = tid;
        int h0 = histL[2 * l], h1 = histL[2 * l + 1];
        int s = h0 + h1, inc = s;
        #pragma unroll
        for (int off = 1; off < 32; off <<= 1) {
            int t = __shfl_up(inc, off);
            if (l >= off) inc += t;
        }
        int base = inc - s;
        rowO[2 * l] = base; rowO[2 * l + 1] = base + h0;
        ofs[2 * l] = base;  ofs[2 * l + 1] = base + h0;
        if (l == 31) rowO[BN] = inc;
    }
    __syncthreads();

    for (int i = tid; i < cntB; i += 256) {
        u32 e = eStage[i];
        int pos = atomicAdd(&ofs[e >> 20], 1);
        csrS[pos] = e & 0xFFFFFu;
    }
    __syncthreads();                                 // eStage dead

    // ---- Phase 1: packed-f16 gather-aggregate (csrS read, aggTb write) ----
    {
        const uint2* __restrict__ B2 = (const uint2*)Bmh;
        const h2 SEL10 = {(_Float16)1.f, (_Float16)0.f};
        const h2 SEL01 = {(_Float16)0.f, (_Float16)1.f};
        const h2 HZ = {(_Float16)0.f, (_Float16)0.f};
        #pragma unroll
        for (int h = 0; h < 4; ++h) {
            int nl = ng * 4 + h;
            int gn = node0 + nl;
            int start = rowO[nl];
            int d = (gn < N) ? (rowO[nl + 1] - start) : 0;
            h2 A0 = u2h2(pa[h][0]), A1 = u2h2(pa[h][1]);
            float ac0 = 0.f, ac1 = 0.f, ac2 = 0.f, ac3 = 0.f;

            int j = 0;
            for (; j + 8 <= d; j += 8) {             // exact 8-batches
                int ss[8];
                uint2 bb[8];
                #pragma unroll
                for (int t = 0; t < 8; ++t) ss[t] = csrS[start + j + t];
                #pragma unroll
                for (int t = 0; t < 8; ++t) bb[t] = B2[(size_t)ss[t] * 16 + q];
                #pragma unroll
                for (int t = 0; t < 8; ++t) {
                    h2 t0 = A0 + u2h2(bb[t].x);
                    h2 t1 = A1 + u2h2(bb[t].y);
                    t0 = __builtin_elementwise_max(t0, HZ);
                    t1 = __builtin_elementwise_max(t1, HZ);
                    ac0 = __builtin_amdgcn_fdot2(t0, SEL10, ac0, false);
                    ac1 = __builtin_amdgcn_fdot2(t0, SEL01, ac1, false);
                    ac2 = __builtin_amdgcn_fdot2(t1, SEL10, ac2, false);
                    ac3 = __builtin_amdgcn_fdot2(t1, SEL01, ac3, false);
                }
            }
            if (j < d) {                             // masked 8-tail: -inf -> relu 0
                int ss[8];
                uint2 bb[8];
                #pragma unroll
                for (int t = 0; t < 8; ++t) ss[t] = csrS[start + min(j + t, d - 1)];
                #pragma unroll
                for (int t = 0; t < 8; ++t) bb[t] = B2[(size_t)ss[t] * 16 + q];
                #pragma unroll
                for (int t = 0; t < 8; ++t) {
                    if (j + t >= d) { bb[t].x = 0xFC00FC00u; bb[t].y = 0xFC00FC00u; }
                    h2 t0 = A0 + u2h2(bb[t].x);
                    h2 t1 = A1 + u2h2(bb[t].y);
                    t0 = __builtin_elementwise_max(t0, HZ);
                    t1 = __builtin_elementwise_max(t1, HZ);
                    ac0 = __builtin_amdgcn_fdot2(t0, SEL10, ac0, false);
                    ac1 = __builtin_amdgcn_fdot2(t0, SEL01, ac1, false);
                    ac2 = __builtin_amdgcn_fdot2(t1, SEL10, ac2, false);
                    ac3 = __builtin_amdgcn_fdot2(t1, SEL01, ac3, false);
                }
            }
            uint2 pk;
            pk.x = f2h(ac0) | (f2h(ac1) << 16);
            pk.y = f2h(ac2) | (f2h(ac3) << 16);
            aggTb[nl * 17 + q] = pk;
        }
    }
    __syncthreads();                                 // csrS dead

    // ---- Stage W2kp over dead csrS/eStage (L2/L3-hot) ----
    // W2kp[kk*64+c] = ( f16(W2[2kk][c]), f16(W2[2kk+1][c]) )
    for (int i = tid; i < 2048; i += 256) {
        int kk = i >> 6, c = i & 63;
        W2kp[i] = f2h(W2[(2 * kk) * 64 + c]) | (f2h(W2[(2 * kk + 1) * 64 + c]) << 16);
    }
    __syncthreads();

    // ---- Phase 2: [64x64] @ W2 via fdot2 + deg*b2, tanh ----
    {
        const int cg = tid & 15, g = tid >> 4;       // g: 0..15 -> 64 nodes
        const int c0 = cg * 4;
        const int nb0 = g * 4;                       // nodes nb0..nb0+3
        float o[4][4];
        #pragma unroll
        for (int ni = 0; ni < 4; ++ni) {
            float dg = (float)(rowO[nb0 + ni + 1] - rowO[nb0 + ni]);
            #pragma unroll
            for (int ci = 0; ci < 4; ++ci) o[ni][ci] = dg * b2s[c0 + ci];
        }
        #pragma unroll 4
        for (int kc = 0; kc < 16; ++kc) {
            uint2 u0 = aggTb[(nb0 + 0) * 17 + kc];
            uint2 u1 = aggTb[(nb0 + 1) * 17 + kc];
            uint2 u2 = aggTb[(nb0 + 2) * 17 + kc];
            uint2 u3 = aggTb[(nb0 + 3) * 17 + kc];
            uint4 wA = *(const uint4*)&W2kp[(2 * kc) * 64 + c0];
            uint4 wB = *(const uint4*)&W2kp[(2 * kc + 1) * 64 + c0];
            h2 wa[4] = {u2h2(wA.x), u2h2(wA.y), u2h2(wA.z), u2h2(wA.w)};
            h2 wb[4] = {u2h2(wB.x), u2h2(wB.y), u2h2(wB.z), u2h2(wB.w)};
            h2 a0x = u2h2(u0.x), a0y = u2h2(u0.y);
            h2 a1x = u2h2(u1.x), a1y = u2h2(u1.y);
            h2 a2x = u2h2(u2.x), a2y = u2h2(u2.y);
            h2 a3x = u2h2(u3.x), a3y = u2h2(u3.y);
            #pragma unroll
            for (int ci = 0; ci < 4; ++ci) {
                o[0][ci] = __builtin_amdgcn_fdot2(a0x, wa[ci], o[0][ci], false);
                o[0][ci] = __builtin_amdgcn_fdot2(a0y, wb[ci], o[0][ci], false);
                o[1][ci] = __builtin_amdgcn_fdot2(a1x, wa[ci], o[1][ci], false);
                o[1][ci] = __builtin_amdgcn_fdot2(a1y, wb[ci], o[1][ci], false);
                o[2][ci] = __builtin_amdgcn_fdot2(a2x, wa[ci], o[2][ci], false);
                o[2][ci] = __builtin_amdgcn_fdot2(a2y, wb[ci], o[2][ci], false);
                o[3][ci] = __builtin_amdgcn_fdot2(a3x, wa[ci], o[3][ci], false);
                o[3][ci] = __builtin_amdgcn_fdot2(a3y, wb[ci], o[3][ci], false);
            }
        }
        #pragma unroll
        for (int ni = 0; ni < 4; ++ni) {
            int gn = node0 + nb0 + ni;
            if (gn < N) {
                float4 r = make_float4(tanhf(o[ni][0]), tanhf(o[ni][1]),
                                       tanhf(o[ni][2]), tanhf(o[ni][3]));
                ((float4*)out)[(size_t)gn * 16 + cg] = r;
            }
        }
    }
}

// ---------------------------------------------------------------------------
extern "C" void kernel_launch(void* const* d_in, const int* in_sizes, int n_in,
                              void* d_out, int out_size, void* d_ws, size_t ws_size,
                              hipStream_t stream)
{
    const float* x  = (const float*)d_in[0];
    const int*   ei = (const int*)d_in[1];     // [2,E]: row0=src, row1=dst
    const float* W1 = (const float*)d_in[2];   // [128,64]
    const float* b1 = (const float*)d_in[3];   // [64]
    const float* W2 = (const float*)d_in[4];   // [64,64]
    const float* b2 = (const float*)d_in[5];   // [64]
    float* out = (float*)d_out;

    const int N = in_sizes[0] / FDIM;          // 100000
    const int E = in_sizes[1] / 2;             // 1200000
    const int NB = (N + BN - 1) / BN;          // 1563 buckets

    // Workspace (re-poisoned 0xAA every call; gcnt zeroed below):
    u16*   Bmh   = (u16*)d_ws;                          // N*64 f16 = 12.8 MB
    u32*   slotB = (u32*)(Bmh + (size_t)N * FDIM);      // NB*CAPB u32 = 6.4 MB
    int*   gcnt  = (int*)(slotB + (size_t)NB * CAPB);   // NB i32

    hipMemsetAsync(gcnt, 0, (size_t)NB * sizeof(int), stream);

    // Interleaved heterogeneous grid: 1 bin block per 6 (idx%6==5), rest pre.
    const int nPre = (N + 63) / 64;            // 1563
    const int nBin = (E + EPB - 1) / EPB;      // 293
    int T = (nPre * 6 + 4) / 5;
    while (T - T / 6 < nPre) ++T;
    if (T < 6 * nBin) T = 6 * nBin;

    prep_k<<<T, 256, 0, stream>>>(x, W1, Bmh, ei, slotB, gcnt,
                                  N, E, NB, nPre, nBin);
    fused_agg<<<NB, 256, 0, stream>>>(x, W1, b1, Bmh, slotB, gcnt, W2, b2, out, N);
}